// Round 13
// baseline (178.950 us; speedup 1.0000x reference)
//
#include <hip/hip_runtime.h>
#include <math.h>

#define Tt 4096
#define Cc 1024
#define Hh 64

typedef __attribute__((ext_vector_type(8))) short bf16x8;
typedef __attribute__((ext_vector_type(4))) float f32x4;
typedef unsigned int u32;

__device__ inline unsigned short f2bf(float f) {
    unsigned u = __float_as_uint(f);
    u = (u + 0x7FFFu + ((u >> 16) & 1u)) >> 16;   // RNE
    return (unsigned short)u;
}

// ---------- W^T bf16 [192][1024]; kScale folded into Wq ----------
__global__ __launch_bounds__(256) void wt_build(
    const float* __restrict__ Wq, const float* __restrict__ Wk,
    const float* __restrict__ Wv, unsigned short* __restrict__ Wt)
{
    int e = blockIdx.x * 256 + threadIdx.x;   // 0..196607
    int k = e & 1023, n = e >> 10;
    float v;
    if (n < 64)       v = Wq[k * 64 + n] * 0.03125f;   // fold 1024^-0.5 into Q
    else if (n < 128) v = Wk[k * 64 + (n - 64)];
    else              v = Wv[k * 64 + (n - 128)];
    Wt[n * 1024 + k] = f2bf(v);
}

// ---------- QKV GEMM v6: 16-row A-tile, 32KB LDS, 4 blocks/CU (16 waves/CU) ----------
// 1024 blocks x 4 waves. Block tile 16M x 192N; wave owns 16M x 48N.
// Staging: 16 independent float4 loads -> convert -> swizzled LDS write (T14).
// K-loop (16 steps, unrolled): 2 ds_read_b128 + 6 global b16x8 (W^T, L2) +
// 6 MFMA per wave-step; reg double-buffer on both; immediate offsets only.
// LDS layout: row*1024 + (elem ^ ((row&7)<<3))  (verified swizzle).
__global__ __launch_bounds__(256, 4) void qkv_gemm(
    const float* __restrict__ x, const unsigned short* __restrict__ wt,
    unsigned short* __restrict__ qb, unsigned short* __restrict__ kb,
    unsigned short* __restrict__ vt)
{
    __shared__ unsigned short as_[16 * 1024];   // 32 KiB

    const int t = threadIdx.x, w = t >> 6, lane = t & 63;
    const int col = lane & 15, quad = lane >> 4;
    const int m0 = blockIdx.x * 16;

    // ---- stage A slab: 16 rows x 1024 K fp32 -> bf16 LDS, batched loads
    {
        const float* xb = x + (long)m0 * Cc;
        float4 vbuf[16];
#pragma unroll
        for (int s = 0; s < 16; ++s)                // 16 independent loads
            vbuf[s] = *(const float4*)&xb[s * 1024 + t * 4];
#pragma unroll
        for (int s = 0; s < 16; ++s) {              // convert + swizzled write
            ushort4 pk = { f2bf(vbuf[s].x), f2bf(vbuf[s].y),
                           f2bf(vbuf[s].z), f2bf(vbuf[s].w) };
            int woff = (t * 4) ^ ((s & 7) << 3);
            *(ushort4*)&as_[s * 1024 + woff] = pk;
        }
    }
    __syncthreads();   // the only barrier

    const unsigned short* aB[2];
#pragma unroll
    for (int kc = 0; kc < 2; ++kc)
        aB[kc] = &as_[col * 1024 + ((kc * 32 + quad * 8) ^ ((col & 7) << 3))];

    const unsigned short* pB[3];
#pragma unroll
    for (int nt = 0; nt < 3; ++nt)
        pB[nt] = wt + ((w * 3 + nt) * 16 + col) * 1024 + quad * 8;

    f32x4 acc[3];
#pragma unroll
    for (int nt = 0; nt < 3; ++nt) acc[nt] = (f32x4){0.f, 0.f, 0.f, 0.f};

    bf16x8 bfr[2][3][2];   // [buf][nt][kc]
    bf16x8 afr[2][2];      // [buf][kc]

#pragma unroll
    for (int nt = 0; nt < 3; ++nt)
#pragma unroll
        for (int kc = 0; kc < 2; ++kc)
            bfr[0][nt][kc] = *(const bf16x8*)(pB[nt] + kc * 32);
#pragma unroll
    for (int kc = 0; kc < 2; ++kc)
        afr[0][kc] = *(const bf16x8*)(aB[kc]);

#pragma unroll
    for (int k = 0; k < 16; ++k) {
        const int cur = k & 1, nxt = cur ^ 1;
        if (k < 15) {
            const int ko = (k + 1) * 64;
#pragma unroll
            for (int nt = 0; nt < 3; ++nt)
#pragma unroll
                for (int kc = 0; kc < 2; ++kc)
                    bfr[nxt][nt][kc] = *(const bf16x8*)(pB[nt] + ko + kc * 32);
#pragma unroll
            for (int kc = 0; kc < 2; ++kc)
                afr[nxt][kc] = *(const bf16x8*)(aB[kc] + ko);
        }
#pragma unroll
        for (int kc = 0; kc < 2; ++kc)
#pragma unroll
            for (int nt = 0; nt < 3; ++nt)
                acc[nt] = __builtin_amdgcn_mfma_f32_16x16x32_bf16(
                    afr[cur][kc], bfr[cur][nt][kc], acc[nt], 0, 0, 0);
    }

    const long bidx = m0 >> 12;
    const int tbase = m0 & 4095;
#pragma unroll
    for (int nt = 0; nt < 3; ++nt) {
        int ntg = w * 3 + nt;
        int n = ntg * 16 + col;
        int row = m0 + quad * 4;
        if (ntg < 4) {
#pragma unroll
            for (int reg = 0; reg < 4; ++reg)
                qb[(long)(row + reg) * Hh + n] = f2bf(acc[nt][reg]);
        } else if (ntg < 8) {
#pragma unroll
            for (int reg = 0; reg < 4; ++reg)
                kb[(long)(row + reg) * Hh + (n - 64)] = f2bf(acc[nt][reg]);
        } else {
            int h = n - 128;
            ushort4 pk = { f2bf(acc[nt][0]), f2bf(acc[nt][1]),
                           f2bf(acc[nt][2]), f2bf(acc[nt][3]) };
            *(ushort4*)&vt[(bidx * Hh + h) * (long)Tt + tbase + quad * 4] = pk;
        }
    }
}

// ---------- flash attention (round-4 proven body, 40.9us): static-max softmax ----------
// 1024 blocks, 2-split; LDS 35.3KB: pl aliased into this wave's own o_red slice.
#define LDP 56
#define LDO 68

__global__ __launch_bounds__(256) void attn(
    const unsigned short* __restrict__ qg, const unsigned short* __restrict__ kg,
    const unsigned short* __restrict__ vtg,
    float* __restrict__ po, float* __restrict__ pls)
{
    __shared__ __align__(16) char smem[35328];
    float* o_red       = (float*)smem;                      // 34816 B
    float* lred        = (float*)(smem + 34816);            // 512 B
    unsigned short* pl = (unsigned short*)smem;             // per-wave slice

    const int p    = blockIdx.x;
    const int qt   = 127 - (p >> 3);
    const int b    = p & 3;
    const int half = (p >> 2) & 1;
    const int tid  = (b << 7) | qt;
    const long qrow0 = (long)b * Tt + qt * 32;
    const int nkt = qt + 1;
    const int n0  = (nkt + 1) >> 1;
    const int cnt = half ? (nkt - n0) : n0;
    const int ust = half ? n0 : 0;

    const int t = threadIdx.x, w = t >> 6, lane = t & 63;
    const int col = lane & 15, quad = lane >> 4;
    const int plbase = w * 4352;   // shorts: wave w's own 8704B o_red slice

    bf16x8 qf[2][2];
#pragma unroll
    for (int mt = 0; mt < 2; ++mt)
#pragma unroll
        for (int kc = 0; kc < 2; ++kc)
            qf[mt][kc] = *(const bf16x8*)&qg[(qrow0 + mt * 16 + col) * Hh + kc * 32 + quad * 8];

    f32x4 oacc[2][4];
#pragma unroll
    for (int mt = 0; mt < 2; ++mt)
#pragma unroll
        for (int nt = 0; nt < 4; ++nt) oacc[mt][nt] = (f32x4){0.f, 0.f, 0.f, 0.f};
    float lsum[2][4] = {{0.f,0.f,0.f,0.f},{0.f,0.f,0.f,0.f}};

    for (int iu = w; iu < cnt; iu += 4) {
        const int u = ust + iu;
        const long krow0 = (long)b * Tt + u * 32;
        bf16x8 kf[2][2];
#pragma unroll
        for (int nt = 0; nt < 2; ++nt)
#pragma unroll
            for (int kc = 0; kc < 2; ++kc)
                kf[nt][kc] = *(const bf16x8*)&kg[(krow0 + nt * 16 + col) * Hh + kc * 32 + quad * 8];
        f32x4 s[2][2];
#pragma unroll
        for (int mt = 0; mt < 2; ++mt)
#pragma unroll
            for (int nt = 0; nt < 2; ++nt) {
                s[mt][nt] = (f32x4){0.f, 0.f, 0.f, 0.f};
#pragma unroll
                for (int kc = 0; kc < 2; ++kc)
                    s[mt][nt] = __builtin_amdgcn_mfma_f32_16x16x32_bf16(qf[mt][kc], kf[nt][kc], s[mt][nt], 0, 0, 0);
            }
#pragma unroll
        for (int mt = 0; mt < 2; ++mt)
#pragma unroll
            for (int reg = 0; reg < 4; ++reg) {
                int rloc = mt * 16 + quad * 4 + reg;
                if (u == qt) {
                    if (col > rloc)      s[mt][0][reg] = -INFINITY;
                    if (16 + col > rloc) s[mt][1][reg] = -INFINITY;
                }
                float p0 = __expf(s[mt][0][reg]);
                float p1 = __expf(s[mt][1][reg]);
                lsum[mt][reg] += p0 + p1;
                pl[plbase + rloc * LDP + col]      = f2bf(p0);
                pl[plbase + rloc * LDP + 16 + col] = f2bf(p1);
            }
        bf16x8 af0 = *(const bf16x8*)&pl[plbase + col * LDP + quad * 8];
        bf16x8 af1 = *(const bf16x8*)&pl[plbase + (16 + col) * LDP + quad * 8];
#pragma unroll
        for (int nt = 0; nt < 4; ++nt) {
            bf16x8 vf = *(const bf16x8*)&vtg[((long)b * Hh + nt * 16 + col) * Tt + u * 32 + quad * 8];
            oacc[0][nt] = __builtin_amdgcn_mfma_f32_16x16x32_bf16(af0, vf, oacc[0][nt], 0, 0, 0);
            oacc[1][nt] = __builtin_amdgcn_mfma_f32_16x16x32_bf16(af1, vf, oacc[1][nt], 0, 0, 0);
        }
    }

#pragma unroll
    for (int mt = 0; mt < 2; ++mt)
#pragma unroll
        for (int reg = 0; reg < 4; ++reg) {
            float l = lsum[mt][reg];
            l += __shfl_xor(l, 1); l += __shfl_xor(l, 2);
            l += __shfl_xor(l, 4); l += __shfl_xor(l, 8);
            if (col == 0) lred[w * 32 + mt * 16 + quad * 4 + reg] = l;
        }
    // wave w's o_red slice = rows [w*32, w*32+32) -- overwrites its own pl
#pragma unroll
    for (int mt = 0; mt < 2; ++mt)
#pragma unroll
        for (int nt = 0; nt < 4; ++nt)
#pragma unroll
            for (int reg = 0; reg < 4; ++reg)
                o_red[(w * 32 + mt * 16 + quad * 4 + reg) * LDO + nt * 16 + col] = oacc[mt][nt][reg];
    __syncthreads();
    if (t < 32)
        pls[(tid * 2 + half) * 32 + t] = lred[t] + lred[32 + t] + lred[64 + t] + lred[96 + t];
    float* pob = po + ((long)tid * 2 + half) * 2048;
#pragma unroll
    for (int j = 0; j < 8; ++j) {
        int e = t + 256 * j, r = e >> 6, c = e & 63;
        pob[e] = o_red[r * LDO + c] + o_red[(32 + r) * LDO + c]
               + o_red[(64 + r) * LDO + c] + o_red[(96 + r) * LDO + c];
    }
}

// ---------- combine: out = (O0+O1)/(l0+l1) ----------
__global__ __launch_bounds__(256) void combine(
    const float* __restrict__ po, const float* __restrict__ pls, float* __restrict__ out)
{
    const int g = blockIdx.x;
    const long orow = (((long)(g >> 7)) * Tt + (long)(g & 127) * 32) * Hh;
    const float* p0 = po + (long)g * 2 * 2048;
    const float* p1 = p0 + 2048;
    const float* l0 = pls + g * 2 * 32;
    const float* l1 = l0 + 32;
    const int t = threadIdx.x;
#pragma unroll
    for (int j = 0; j < 8; ++j) {
        int e = t + 256 * j, r = e >> 6;
        out[orow + e] = (p0[e] + p1[e]) / (l0[r] + l1[r]);
    }
}

extern "C" void kernel_launch(void* const* d_in, const int* in_sizes, int n_in,
                              void* d_out, int out_size, void* d_ws, size_t ws_size,
                              hipStream_t stream)
{
    const float* x  = (const float*)d_in[0];
    const float* Wq = (const float*)d_in[1];
    const float* Wk = (const float*)d_in[2];
    const float* Wv = (const float*)d_in[3];
    float* outp = (float*)d_out;

    unsigned short* wt = (unsigned short*)d_ws;       // 192*1024 bf16 (384 KB)
    unsigned short* qb = wt + 196608;                 // 2 MB
    unsigned short* kb = qb + 1048576;                // 2 MB
    unsigned short* vt = kb + 1048576;                // V^T [b][h][t] (2 MB)
    float* po  = (float*)(vt + 1048576);              // [512][2][2048] (8 MB)
    float* pls = po + 2097152;                        // [512][2][32]

    wt_build<<<dim3(768), dim3(256), 0, stream>>>(Wq, Wk, Wv, wt);
    qkv_gemm<<<dim3(1024), dim3(256), 0, stream>>>(x, wt, qb, kb, vt);
    attn<<<dim3(1024), dim3(256), 0, stream>>>(qb, kb, vt, po, pls);
    combine<<<dim3(512), dim3(256), 0, stream>>>(po, pls, outp);
}

// Round 14
// 131.096 us; speedup vs baseline: 1.3650x; 1.3650x over previous
//
#include <hip/hip_runtime.h>
#include <math.h>

#define Tt 4096
#define Cc 1024
#define Hh 64

typedef __attribute__((ext_vector_type(8))) short bf16x8;
typedef __attribute__((ext_vector_type(4))) float f32x4;
typedef unsigned int u32;

__device__ inline unsigned short f2bf(float f) {
    unsigned u = __float_as_uint(f);
    u = (u + 0x7FFFu + ((u >> 16) & 1u)) >> 16;   // RNE
    return (unsigned short)u;
}

// ---------- W^T in B-FRAGMENT order: [ntg(12)][ks(16)][kc(2)][lane(64)][j(8)] ----------
// Element (n = ntg*16+col, k = ks*64 + kc*32 + quad*8 + j), lane = quad*16+col.
// kScale folded into Wq. Each qkv wave-load of a fragment = contiguous 1KB.
__global__ __launch_bounds__(256) void wt_build(
    const float* __restrict__ Wq, const float* __restrict__ Wk,
    const float* __restrict__ Wv, unsigned short* __restrict__ Wt)
{
    int e = blockIdx.x * 256 + threadIdx.x;   // 0..196607
    int j    = e & 7;
    int lane = (e >> 3) & 63;
    int kc   = (e >> 9) & 1;
    int ks   = (e >> 10) & 15;
    int ntg  = e >> 14;
    int col = lane & 15, quad = lane >> 4;
    int n = ntg * 16 + col;
    int k = ks * 64 + kc * 32 + quad * 8 + j;
    float v;
    if (n < 64)       v = Wq[k * 64 + n] * 0.03125f;   // fold 1024^-0.5 into Q
    else if (n < 128) v = Wk[k * 64 + (n - 64)];
    else              v = Wv[k * 64 + (n - 128)];
    Wt[e] = f2bf(v);
}

// ---------- QKV GEMM v7: v5 structure (32M tile, 45us proven) + coalesced B ----------
// 512 blocks x 4 waves, 2 blocks/CU. B loads: contiguous 1KB per wave-instr
// (fragment-major wt). Outputs written in attn-fragment order:
//   qbf/kbf: [tile(512)][mt*2+kc (4)][lane(64)][8]   (tile = 32 rows)
//   vtf:     [tile(512)][nt (4)][lane(64)][8]
__global__ __launch_bounds__(256, 2) void qkv_gemm(
    const float* __restrict__ x, const unsigned short* __restrict__ wt,
    unsigned short* __restrict__ qb, unsigned short* __restrict__ kb,
    unsigned short* __restrict__ vt)
{
    __shared__ unsigned short as_[32 * 1024];   // 64 KiB

    const int t = threadIdx.x, w = t >> 6, lane = t & 63;
    const int col = lane & 15, quad = lane >> 4;
    const int m0 = blockIdx.x * 32;

    // ---- stage A slab: 32 rows x 1024 K fp32 -> bf16 LDS, batched loads
    {
        const float* xb = x + (long)m0 * Cc;
        float4 vbuf[16];
#pragma unroll
        for (int g = 0; g < 2; ++g) {
#pragma unroll
            for (int s = 0; s < 16; ++s) {          // 16 independent loads
                int row = g * 16 + s;
                vbuf[s] = *(const float4*)&xb[row * 1024 + t * 4];
            }
#pragma unroll
            for (int s = 0; s < 16; ++s) {          // convert + swizzled write
                int row = g * 16 + s;
                ushort4 pk = { f2bf(vbuf[s].x), f2bf(vbuf[s].y),
                               f2bf(vbuf[s].z), f2bf(vbuf[s].w) };
                int woff = (t * 4) ^ ((row & 7) << 3);
                *(ushort4*)&as_[row * 1024 + woff] = pk;
            }
        }
    }
    __syncthreads();   // the only barrier

    const unsigned short* aB[2];
#pragma unroll
    for (int kc = 0; kc < 2; ++kc)
        aB[kc] = &as_[col * 1024 + ((kc * 32 + quad * 8) ^ ((col & 7) << 3))];

    // B fragment base: wave w owns n-tiles w*3..w*3+2; contiguous 1KB/load
    const unsigned short* pB[3];
#pragma unroll
    for (int nt = 0; nt < 3; ++nt)
        pB[nt] = wt + (w * 3 + nt) * 16384 + lane * 8;
    // read: pB[nt] + k*1024 + kc*512   (pure immediates)

    f32x4 acc[2][3];
#pragma unroll
    for (int mt = 0; mt < 2; ++mt)
#pragma unroll
        for (int nt = 0; nt < 3; ++nt) acc[mt][nt] = (f32x4){0.f, 0.f, 0.f, 0.f};

    bf16x8 bfr[2][3][2];   // [buf][nt][kc]
    bf16x8 afr[2][2][2];   // [buf][mt][kc]

#pragma unroll
    for (int nt = 0; nt < 3; ++nt)
#pragma unroll
        for (int kc = 0; kc < 2; ++kc)
            bfr[0][nt][kc] = *(const bf16x8*)(pB[nt] + kc * 512);
#pragma unroll
    for (int mt = 0; mt < 2; ++mt)
#pragma unroll
        for (int kc = 0; kc < 2; ++kc)
            afr[0][mt][kc] = *(const bf16x8*)(aB[kc] + mt * 16 * 1024);

#pragma unroll
    for (int k = 0; k < 16; ++k) {
        const int cur = k & 1, nxt = cur ^ 1;
        if (k < 15) {
            const int ko = (k + 1) * 64;
#pragma unroll
            for (int nt = 0; nt < 3; ++nt)
#pragma unroll
                for (int kc = 0; kc < 2; ++kc)
                    bfr[nxt][nt][kc] = *(const bf16x8*)(pB[nt] + (k + 1) * 1024 + kc * 512);
#pragma unroll
            for (int mt = 0; mt < 2; ++mt)
#pragma unroll
                for (int kc = 0; kc < 2; ++kc)
                    afr[nxt][mt][kc] = *(const bf16x8*)(aB[kc] + mt * 16 * 1024 + ko);
        }
#pragma unroll
        for (int kc = 0; kc < 2; ++kc)
#pragma unroll
            for (int nt = 0; nt < 3; ++nt)
#pragma unroll
                for (int mt = 0; mt < 2; ++mt)
                    acc[mt][nt] = __builtin_amdgcn_mfma_f32_16x16x32_bf16(
                        afr[cur][mt][kc], bfr[cur][nt][kc], acc[mt][nt], 0, 0, 0);
    }

    // ---- epilogue: fragment-major outputs. tile = m0>>5 (= b*128 + t-tile)
    const int tile = m0 >> 5;
#pragma unroll
    for (int mt = 0; mt < 2; ++mt)
#pragma unroll
        for (int nt = 0; nt < 3; ++nt) {
            int ntg = w * 3 + nt;
            if (ntg < 4) {
                // Q: h = ntg*16+col = kcF*32 + quadF*8 + jF; colF = quad*4+reg
                int kcF   = ntg >> 1;
                int quadF = ((ntg & 1) << 1) | (col >> 3);
                int jF    = col & 7;
                long base = ((long)(tile * 4 + mt * 2 + kcF)) * 512
                          + (quadF * 16 + quad * 4) * 8 + jF;
#pragma unroll
                for (int reg = 0; reg < 4; ++reg)
                    qb[base + reg * 8] = f2bf(acc[mt][nt][reg]);
            } else if (ntg < 8) {
                // K: rows are t-dim (ntF = mt); h = (ntg-4)*16+col
                int h = (ntg - 4) * 16 + col;
                int kcF   = h >> 5;
                int quadF = (h >> 3) & 3;
                int jF    = h & 7;
                long base = ((long)(tile * 4 + mt * 2 + kcF)) * 512
                          + (quadF * 16 + quad * 4) * 8 + jF;
#pragma unroll
                for (int reg = 0; reg < 4; ++reg)
                    kb[base + reg * 8] = f2bf(acc[mt][nt][reg]);
            } else {
                // V: ntF = ntg-8; t-offset toff = mt*16 + quad*4 + reg
                int ntF = ntg - 8;
                int toff0 = mt * 16 + quad * 4;
                long base = ((long)(tile * 4 + ntF)) * 512
                          + ((toff0 >> 3) * 16 + col) * 8 + (toff0 & 7);
                ushort4 pk = { f2bf(acc[mt][nt][0]), f2bf(acc[mt][nt][1]),
                               f2bf(acc[mt][nt][2]), f2bf(acc[mt][nt][3]) };
                *(ushort4*)&vt[base] = pk;
            }
        }
}

// ---------- flash attention (round-4 proven body) + fragment-major coalesced loads ----------
// 1024 blocks, 2-split; LDS 35.3KB: pl aliased into this wave's own o_red slice.
// Q/K/V loads are now contiguous 1KB per wave-instr: base + u*2048 + slot*512 + lane*8.
#define LDP 56
#define LDO 68

__global__ __launch_bounds__(256) void attn(
    const unsigned short* __restrict__ qg, const unsigned short* __restrict__ kg,
    const unsigned short* __restrict__ vtg,
    float* __restrict__ po, float* __restrict__ pls)
{
    __shared__ __align__(16) char smem[35328];
    float* o_red       = (float*)smem;                      // 34816 B
    float* lred        = (float*)(smem + 34816);            // 512 B
    unsigned short* pl = (unsigned short*)smem;             // per-wave slice

    const int p    = blockIdx.x;
    const int qt   = 127 - (p >> 3);
    const int b    = p & 3;
    const int half = (p >> 2) & 1;
    const int tid  = (b << 7) | qt;
    const int nkt = qt + 1;
    const int n0  = (nkt + 1) >> 1;
    const int cnt = half ? (nkt - n0) : n0;
    const int ust = half ? n0 : 0;

    const int t = threadIdx.x, w = t >> 6, lane = t & 63;
    const int col = lane & 15, quad = lane >> 4;
    const int plbase = w * 4352;   // shorts: wave w's own 8704B o_red slice

    const unsigned short* qbb = qg  + ((long)(b * 128 + qt)) * 2048 + lane * 8;
    const unsigned short* kbb = kg  + ((long)b * 128) * 2048 + lane * 8;
    const unsigned short* vbb = vtg + ((long)b * 128) * 2048 + lane * 8;

    bf16x8 qf[2][2];
#pragma unroll
    for (int mt = 0; mt < 2; ++mt)
#pragma unroll
        for (int kc = 0; kc < 2; ++kc)
            qf[mt][kc] = *(const bf16x8*)(qbb + (mt * 2 + kc) * 512);

    f32x4 oacc[2][4];
#pragma unroll
    for (int mt = 0; mt < 2; ++mt)
#pragma unroll
        for (int nt = 0; nt < 4; ++nt) oacc[mt][nt] = (f32x4){0.f, 0.f, 0.f, 0.f};
    float lsum[2][4] = {{0.f,0.f,0.f,0.f},{0.f,0.f,0.f,0.f}};

    for (int iu = w; iu < cnt; iu += 4) {
        const int u = ust + iu;
        const unsigned short* ku = kbb + u * 2048;
        const unsigned short* vu = vbb + u * 2048;
        bf16x8 kf[2][2];
#pragma unroll
        for (int nt = 0; nt < 2; ++nt)
#pragma unroll
            for (int kc = 0; kc < 2; ++kc)
                kf[nt][kc] = *(const bf16x8*)(ku + (nt * 2 + kc) * 512);
        f32x4 s[2][2];
#pragma unroll
        for (int mt = 0; mt < 2; ++mt)
#pragma unroll
            for (int nt = 0; nt < 2; ++nt) {
                s[mt][nt] = (f32x4){0.f, 0.f, 0.f, 0.f};
#pragma unroll
                for (int kc = 0; kc < 2; ++kc)
                    s[mt][nt] = __builtin_amdgcn_mfma_f32_16x16x32_bf16(qf[mt][kc], kf[nt][kc], s[mt][nt], 0, 0, 0);
            }
#pragma unroll
        for (int mt = 0; mt < 2; ++mt)
#pragma unroll
            for (int reg = 0; reg < 4; ++reg) {
                int rloc = mt * 16 + quad * 4 + reg;
                if (u == qt) {
                    if (col > rloc)      s[mt][0][reg] = -INFINITY;
                    if (16 + col > rloc) s[mt][1][reg] = -INFINITY;
                }
                float p0 = __expf(s[mt][0][reg]);
                float p1 = __expf(s[mt][1][reg]);
                lsum[mt][reg] += p0 + p1;
                pl[plbase + rloc * LDP + col]      = f2bf(p0);
                pl[plbase + rloc * LDP + 16 + col] = f2bf(p1);
            }
        bf16x8 af0 = *(const bf16x8*)&pl[plbase + col * LDP + quad * 8];
        bf16x8 af1 = *(const bf16x8*)&pl[plbase + (16 + col) * LDP + quad * 8];
#pragma unroll
        for (int nt = 0; nt < 4; ++nt) {
            bf16x8 vf = *(const bf16x8*)(vu + nt * 512);
            oacc[0][nt] = __builtin_amdgcn_mfma_f32_16x16x32_bf16(af0, vf, oacc[0][nt], 0, 0, 0);
            oacc[1][nt] = __builtin_amdgcn_mfma_f32_16x16x32_bf16(af1, vf, oacc[1][nt], 0, 0, 0);
        }
    }

#pragma unroll
    for (int mt = 0; mt < 2; ++mt)
#pragma unroll
        for (int reg = 0; reg < 4; ++reg) {
            float l = lsum[mt][reg];
            l += __shfl_xor(l, 1); l += __shfl_xor(l, 2);
            l += __shfl_xor(l, 4); l += __shfl_xor(l, 8);
            if (col == 0) lred[w * 32 + mt * 16 + quad * 4 + reg] = l;
        }
    // wave w's o_red slice = rows [w*32, w*32+32) -- overwrites its own pl
#pragma unroll
    for (int mt = 0; mt < 2; ++mt)
#pragma unroll
        for (int nt = 0; nt < 4; ++nt)
#pragma unroll
            for (int reg = 0; reg < 4; ++reg)
                o_red[(w * 32 + mt * 16 + quad * 4 + reg) * LDO + nt * 16 + col] = oacc[mt][nt][reg];
    __syncthreads();
    if (t < 32)
        pls[(tid * 2 + half) * 32 + t] = lred[t] + lred[32 + t] + lred[64 + t] + lred[96 + t];
    float* pob = po + ((long)tid * 2 + half) * 2048;
#pragma unroll
    for (int j = 0; j < 8; ++j) {
        int e = t + 256 * j, r = e >> 6, c = e & 63;
        pob[e] = o_red[r * LDO + c] + o_red[(32 + r) * LDO + c]
               + o_red[(64 + r) * LDO + c] + o_red[(96 + r) * LDO + c];
    }
}

// ---------- combine: out = (O0+O1)/(l0+l1) ----------
__global__ __launch_bounds__(256) void combine(
    const float* __restrict__ po, const float* __restrict__ pls, float* __restrict__ out)
{
    const int g = blockIdx.x;
    const long orow = (((long)(g >> 7)) * Tt + (long)(g & 127) * 32) * Hh;
    const float* p0 = po + (long)g * 2 * 2048;
    const float* p1 = p0 + 2048;
    const float* l0 = pls + g * 2 * 32;
    const float* l1 = l0 + 32;
    const int t = threadIdx.x;
#pragma unroll
    for (int j = 0; j < 8; ++j) {
        int e = t + 256 * j, r = e >> 6;
        out[orow + e] = (p0[e] + p1[e]) / (l0[r] + l1[r]);
    }
}

extern "C" void kernel_launch(void* const* d_in, const int* in_sizes, int n_in,
                              void* d_out, int out_size, void* d_ws, size_t ws_size,
                              hipStream_t stream)
{
    const float* x  = (const float*)d_in[0];
    const float* Wq = (const float*)d_in[1];
    const float* Wk = (const float*)d_in[2];
    const float* Wv = (const float*)d_in[3];
    float* outp = (float*)d_out;

    unsigned short* wt = (unsigned short*)d_ws;       // 192*1024 bf16 (384 KB, fragment-major)
    unsigned short* qb = wt + 196608;                 // 2 MB (fragment-major Q)
    unsigned short* kb = qb + 1048576;                // 2 MB (fragment-major K)
    unsigned short* vt = kb + 1048576;                // 2 MB (fragment-major V)
    float* po  = (float*)(vt + 1048576);              // [512][2][2048] (8 MB)
    float* pls = po + 2097152;                        // [512][2][32]

    wt_build<<<dim3(768), dim3(256), 0, stream>>>(Wq, Wk, Wv, wt);
    qkv_gemm<<<dim3(512), dim3(256), 0, stream>>>(x, wt, qb, kb, vt);
    attn<<<dim3(1024), dim3(256), 0, stream>>>(qb, kb, vt, po, pls);
    combine<<<dim3(512), dim3(256), 0, stream>>>(po, pls, outp);
}